// Round 1
// baseline (580.689 us; speedup 1.0000x reference)
//
#include <hip/hip_runtime.h>
#include <math.h>

#define Bb 16
#define Hh 48
#define Ww 160
#define Cc 512
#define Gg 8
#define SHI 64
#define Nn (Hh * Ww)          // 7680
#define NCHUNK 16
#define CHUNK (Nn / NCHUNK)   // 480
#define LN_EPS 1e-3f

// ---------------- reductions ----------------
__device__ __forceinline__ float wave_sum(float v) {
#pragma unroll
    for (int o = 32; o > 0; o >>= 1) v += __shfl_xor(v, o);
    return v;
}
__device__ __forceinline__ float wave_max(float v) {
#pragma unroll
    for (int o = 32; o > 0; o >>= 1) v = fmaxf(v, __shfl_xor(v, o));
    return v;
}

// ---------------- K1: attention logits ----------------
// one wave per (b, n); lane l covers channels [8l, 8l+8) -> header l/8
__global__ __launch_bounds__(256) void k_logits(const float* __restrict__ x,
                                                const float* __restrict__ w_mask,
                                                const float* __restrict__ b_mask,
                                                float* __restrict__ logits) {
    int wave = (blockIdx.x * 256 + threadIdx.x) >> 6;
    int lane = threadIdx.x & 63;
    if (wave >= Bb * Nn) return;
    const float* xp = x + (size_t)wave * Cc + lane * 8;
    float4 a0 = *(const float4*)(xp);
    float4 a1 = *(const float4*)(xp + 4);
    int cw = (lane & 7) * 8;  // channel within header
    float4 m0 = *(const float4*)(w_mask + cw);
    float4 m1 = *(const float4*)(w_mask + cw + 4);
    float s = a0.x * m0.x + a0.y * m0.y + a0.z * m0.z + a0.w * m0.w
            + a1.x * m1.x + a1.y * m1.y + a1.z * m1.z + a1.w * m1.w;
    s += __shfl_xor(s, 1);
    s += __shfl_xor(s, 2);
    s += __shfl_xor(s, 4);
    if ((lane & 7) == 0) {
        int g = lane >> 3;
        int b = wave / Nn;
        int n = wave - b * Nn;
        logits[((size_t)b * Gg + g) * Nn + n] = (s + b_mask[0]) * 0.125f;
    }
}

// ---------------- K2: softmax over N per (b,g) ----------------
__global__ __launch_bounds__(256) void k_softmax(const float* __restrict__ logits,
                                                 float* __restrict__ attn) {
    int row = blockIdx.x;  // b*G+g
    const float* lp = logits + (size_t)row * Nn;
    float* ap = attn + (size_t)row * Nn;
    int t = threadIdx.x, lane = t & 63, wid = t >> 6;
    __shared__ float red[4];

    float m = -1e30f;
    for (int i = t; i < Nn; i += 256) m = fmaxf(m, lp[i]);
    m = wave_max(m);
    if (lane == 0) red[wid] = m;
    __syncthreads();
    float M = fmaxf(fmaxf(red[0], red[1]), fmaxf(red[2], red[3]));
    __syncthreads();

    float s = 0.f;
    for (int i = t; i < Nn; i += 256) {
        float e = __expf(lp[i] - M);
        ap[i] = e;
        s += e;
    }
    s = wave_sum(s);
    if (lane == 0) red[wid] = s;
    __syncthreads();
    float inv = 1.0f / (red[0] + red[1] + red[2] + red[3]);
    for (int i = t; i < Nn; i += 256) ap[i] *= inv;
}

// ---------------- K3: ctx partial = sum_n attn[n] * xh[n, c] ----------------
// block = (b, g, chunk); 256 threads: c = t&63, n-offset = t>>6
__global__ __launch_bounds__(256) void k_ctx(const float* __restrict__ x,
                                             const float* __restrict__ attn,
                                             float* __restrict__ partial) {
    int blk = blockIdx.x;
    int chunk = blk & (NCHUNK - 1);
    int g = (blk >> 4) & 7;
    int b = blk >> 7;
    int t = threadIdx.x;
    int c = t & 63;
    int nb = t >> 6;  // 0..3

    const float* xp = x + (size_t)b * Nn * Cc + (size_t)g * SHI + c;
    const float* ap = attn + ((size_t)b * Gg + g) * Nn;

    float acc = 0.f;
    int n0 = chunk * CHUNK + nb;
    int n1 = chunk * CHUNK + CHUNK;
#pragma unroll 8
    for (int n = n0; n < n1; n += 4) {
        acc += ap[n] * xp[(size_t)n * Cc];
    }

    __shared__ float red[256];
    red[t] = acc;
    __syncthreads();
    if (t < 64) {
        float v = red[t] + red[t + 64] + red[t + 128] + red[t + 192];
        partial[(size_t)chunk * (Bb * Cc) + (size_t)b * Cc + g * SHI + t] = v;
    }
}

// ---------------- K4: ctx -> w1 -> LN -> ReLU -> w2 -> t ----------------
__global__ __launch_bounds__(512) void k_mlp(const float* __restrict__ partial,
                                             const float* __restrict__ w1,
                                             const float* __restrict__ b1,
                                             const float* __restrict__ gamma,
                                             const float* __restrict__ beta,
                                             const float* __restrict__ w2,
                                             const float* __restrict__ b2,
                                             float* __restrict__ tvec) {
    int b = blockIdx.x;
    int c = threadIdx.x;  // 0..511
    int lane = c & 63, wid = c >> 6;
    __shared__ float cs[Cc];
    __shared__ float hs[Cc];
    __shared__ float red[8];

    // reduce ctx partials over chunks
    float cv = 0.f;
#pragma unroll
    for (int k = 0; k < NCHUNK; ++k) cv += partial[(size_t)k * (Bb * Cc) + (size_t)b * Cc + c];
    cs[c] = cv;
    __syncthreads();

    // h = ctx @ w1 + b1
    float h = b1[c];
#pragma unroll 8
    for (int k = 0; k < Cc; ++k) h = fmaf(cs[k], w1[(size_t)k * Cc + c], h);

    // LayerNorm (two-pass)
    float s = wave_sum(h);
    if (lane == 0) red[wid] = s;
    __syncthreads();
    float mu = 0.f;
#pragma unroll
    for (int k = 0; k < 8; ++k) mu += red[k];
    mu *= (1.0f / Cc);
    __syncthreads();
    float d = h - mu;
    float sq = wave_sum(d * d);
    if (lane == 0) red[wid] = sq;
    __syncthreads();
    float var = 0.f;
#pragma unroll
    for (int k = 0; k < 8; ++k) var += red[k];
    var *= (1.0f / Cc);
    float hn = d * rsqrtf(var + LN_EPS) * gamma[c] + beta[c];
    hs[c] = fmaxf(hn, 0.f);
    __syncthreads();

    // t = relu(hn) @ w2 + b2
    float tv = b2[c];
#pragma unroll 8
    for (int k = 0; k < Cc; ++k) tv = fmaf(hs[k], w2[(size_t)k * Cc + c], tv);
    tvec[(size_t)b * Cc + c] = tv;
}

// ---------------- K5: out = x + t[b, :, :, c] ----------------
__global__ __launch_bounds__(256) void k_resid(const float4* __restrict__ x4,
                                               const float4* __restrict__ t4,
                                               float4* __restrict__ o4) {
    int b = blockIdx.y;
    int idx = blockIdx.x * 256 + threadIdx.x;  // 0 .. N*C/4-1 (983040)
    int c4 = idx & 127;
    size_t off = (size_t)b * (Nn * (Cc / 4)) + idx;
    float4 xv = x4[off];
    float4 tv = t4[b * (Cc / 4) + c4];
    o4[off] = make_float4(xv.x + tv.x, xv.y + tv.y, xv.z + tv.z, xv.w + tv.w);
}

extern "C" void kernel_launch(void* const* d_in, const int* in_sizes, int n_in,
                              void* d_out, int out_size, void* d_ws, size_t ws_size,
                              hipStream_t stream) {
    const float* x      = (const float*)d_in[0];
    const float* w_mask = (const float*)d_in[1];
    const float* b_mask = (const float*)d_in[2];
    const float* w1     = (const float*)d_in[3];
    const float* b1     = (const float*)d_in[4];
    const float* gamma  = (const float*)d_in[5];
    const float* beta   = (const float*)d_in[6];
    const float* w2     = (const float*)d_in[7];
    const float* b2     = (const float*)d_in[8];
    float* out = (float*)d_out;

    float* ws      = (float*)d_ws;
    float* logits  = ws;                               // B*G*N = 983040
    float* attn    = logits + (size_t)Bb * Gg * Nn;    // 983040
    float* partial = attn + (size_t)Bb * Gg * Nn;      // NCHUNK*B*C = 131072
    float* tvec    = partial + (size_t)NCHUNK * Bb * Cc;  // 8192

    // K1: logits — one wave per (b,n): B*N waves / 4 per block
    k_logits<<<(Bb * Nn) / 4, 256, 0, stream>>>(x, w_mask, b_mask, logits);
    // K2: softmax per (b,g)
    k_softmax<<<Bb * Gg, 256, 0, stream>>>(logits, attn);
    // K3: attention pooling partials
    k_ctx<<<Bb * Gg * NCHUNK, 256, 0, stream>>>(x, attn, partial);
    // K4: MLP + LayerNorm
    k_mlp<<<Bb, Cc, 0, stream>>>(partial, w1, b1, gamma, beta, w2, b2, tvec);
    // K5: residual broadcast add
    k_resid<<<dim3((Nn * Cc / 4) / 256, Bb), 256, 0, stream>>>(
        (const float4*)x, (const float4*)tvec, (float4*)out);
}

// Round 9
// 536.813 us; speedup vs baseline: 1.0817x; 1.0817x over previous
//
#include <hip/hip_runtime.h>
#include <math.h>

#define Bb 16
#define Hh 48
#define Ww 160
#define Cc 512
#define Gg 8
#define SHI 64
#define Nn (Hh * Ww)          // 7680
#define NCH 64                // chunks per batch for fused pool
#define POSCH (Nn / NCH)      // 120 positions per chunk
#define LN_EPS 1e-3f

typedef float v4f __attribute__((ext_vector_type(4)));  // native vec for nt builtins

// ---------------- reductions ----------------
__device__ __forceinline__ float wave_sum(float v) {
#pragma unroll
    for (int o = 32; o > 0; o >>= 1) v += __shfl_xor(v, o);
    return v;
}
__device__ __forceinline__ float wave_max(float v) {
#pragma unroll
    for (int o = 32; o > 0; o >>= 1) v = fmaxf(v, __shfl_xor(v, o));
    return v;
}

// ---------------- KA: fused logits + online-softmax pooling ----------------
// block = (chunk, b); 256 threads = 4 waves. Each wave handles positions
// p = wave, wave+4, ... within the chunk. Lane l covers channels 8l..8l+7
// (header g = l>>3). Online softmax per header, merged across waves in LDS.
__global__ __launch_bounds__(256) void k_pool(const float* __restrict__ x,
                                              const float* __restrict__ w_mask,
                                              const float* __restrict__ b_mask,
                                              float* __restrict__ pctx,   // [B][NCH][C]
                                              float* __restrict__ pms) {  // [B][G][NCH][2]
    int chunk = blockIdx.x;
    int b = blockIdx.y;
    int t = threadIdx.x;
    int w = t >> 6;       // wave 0..3
    int lane = t & 63;
    int g = lane >> 3;

    int cw = (lane & 7) * 8;  // channel within header
    float4 m0 = *(const float4*)(w_mask + cw);
    float4 m1 = *(const float4*)(w_mask + cw + 4);
    float bm = b_mask[0];

    float mrun = -1e30f, srun = 0.f;
    float acc[8];
#pragma unroll
    for (int j = 0; j < 8; ++j) acc[j] = 0.f;

    const float* xbase = x + ((size_t)b * Nn + (size_t)chunk * POSCH) * Cc + lane * 8;

    for (int p = w; p < POSCH; p += 4) {
        const float* xp = xbase + (size_t)p * Cc;
        float4 a0 = *(const float4*)(xp);
        float4 a1 = *(const float4*)(xp + 4);
        float v[8] = {a0.x, a0.y, a0.z, a0.w, a1.x, a1.y, a1.z, a1.w};
        float d = a0.x * m0.x + a0.y * m0.y + a0.z * m0.z + a0.w * m0.w
                + a1.x * m1.x + a1.y * m1.y + a1.z * m1.z + a1.w * m1.w;
        d += __shfl_xor(d, 1);
        d += __shfl_xor(d, 2);
        d += __shfl_xor(d, 4);   // all 8 lanes of group hold header dot
        float l = (d + bm) * 0.125f;
        float mnew = fmaxf(mrun, l);
        float scale = __expf(mrun - mnew);  // ==1 when max unchanged
        float e = __expf(l - mnew);
        srun = srun * scale + e;
#pragma unroll
        for (int j = 0; j < 8; ++j) acc[j] = acc[j] * scale + e * v[j];
        mrun = mnew;
    }

    // merge 4 waves via LDS
    __shared__ float lm[4][8], lsv[4][8];
    __shared__ float lacc[4][Cc];
    if ((lane & 7) == 0) { lm[w][g] = mrun; lsv[w][g] = srun; }
    __syncthreads();
    float M = fmaxf(fmaxf(lm[0][g], lm[1][g]), fmaxf(lm[2][g], lm[3][g]));
    float wscale = __expf(mrun - M);
#pragma unroll
    for (int j = 0; j < 8; ++j) lacc[w][lane * 8 + j] = acc[j] * wscale;
    __syncthreads();
    for (int c = t; c < Cc; c += 256) {
        float s4 = lacc[0][c] + lacc[1][c] + lacc[2][c] + lacc[3][c];
        pctx[((size_t)b * NCH + chunk) * Cc + c] = s4;
    }
    if (t < 8) {
        int gg = t;
        float Mg = fmaxf(fmaxf(lm[0][gg], lm[1][gg]), fmaxf(lm[2][gg], lm[3][gg]));
        float Sg = lsv[0][gg] * __expf(lm[0][gg] - Mg) + lsv[1][gg] * __expf(lm[1][gg] - Mg)
                 + lsv[2][gg] * __expf(lm[2][gg] - Mg) + lsv[3][gg] * __expf(lm[3][gg] - Mg);
        pms[(((size_t)b * Gg + gg) * NCH + chunk) * 2 + 0] = Mg;
        pms[(((size_t)b * Gg + gg) * NCH + chunk) * 2 + 1] = Sg;
    }
}

// ---------------- KB: combine chunks + MLP (w1 -> LN -> ReLU -> w2) --------
__global__ __launch_bounds__(512) void k_mlp(const float* __restrict__ pctx,
                                             const float* __restrict__ pms,
                                             const float* __restrict__ w1,
                                             const float* __restrict__ b1,
                                             const float* __restrict__ gamma,
                                             const float* __restrict__ beta,
                                             const float* __restrict__ w2,
                                             const float* __restrict__ b2,
                                             float* __restrict__ tvec) {
    int b = blockIdx.x;
    int t = threadIdx.x;  // 0..511
    int lane = t & 63, wid = t >> 6;
    __shared__ float escale[Gg][NCH];
    __shared__ float Sg[Gg];
    __shared__ float cs[Cc];
    __shared__ float hs[Cc];
    __shared__ float red[8];

    // phase 1: wave `wid` handles header g=wid; lane = chunk
    {
        int g = wid, ch = lane;
        float2 msv = *(const float2*)(pms + (((size_t)b * Gg + g) * NCH + ch) * 2);
        float M = wave_max(msv.x);
        float e = __expf(msv.x - M);
        escale[g][ch] = e;
        float S = wave_sum(msv.y * e);
        if (lane == 0) Sg[g] = S;
    }
    __syncthreads();

    // phase 2: combine partial ctx
    {
        int g = t >> 6;
        float invS = 1.0f / Sg[g];
        float a = 0.f;
#pragma unroll 4
        for (int ch = 0; ch < NCH; ++ch)
            a += pctx[((size_t)b * NCH + ch) * Cc + t] * escale[g][ch];
        cs[t] = a * invS;
    }
    __syncthreads();

    // h = ctx @ w1 + b1
    float h = b1[t];
#pragma unroll 8
    for (int k = 0; k < Cc; ++k) h = fmaf(cs[k], w1[(size_t)k * Cc + t], h);

    // LayerNorm (two-pass)
    float s = wave_sum(h);
    if (lane == 0) red[wid] = s;
    __syncthreads();
    float mu = 0.f;
#pragma unroll
    for (int k = 0; k < 8; ++k) mu += red[k];
    mu *= (1.0f / Cc);
    __syncthreads();
    float d = h - mu;
    float sq = wave_sum(d * d);
    if (lane == 0) red[wid] = sq;
    __syncthreads();
    float var = 0.f;
#pragma unroll
    for (int k = 0; k < 8; ++k) var += red[k];
    var *= (1.0f / Cc);
    float hn = d * rsqrtf(var + LN_EPS) * gamma[t] + beta[t];
    hs[t] = fmaxf(hn, 0.f);
    __syncthreads();

    // t = relu(hn) @ w2 + b2
    float tv = b2[t];
#pragma unroll 8
    for (int k = 0; k < Cc; ++k) tv = fmaf(hs[k], w2[(size_t)k * Cc + t], tv);
    tvec[(size_t)b * Cc + t] = tv;
}

// ---------------- KC: out = x + t[b, c] ----------------
// 2x 16B per thread; non-temporal load of x (last use) and non-temporal
// store of out (write-only) — avoid polluting L2/L3, which x wants across
// graph-replay iterations. Uses native ext_vector_type for the nt builtins.
__global__ __launch_bounds__(256) void k_resid(const v4f* __restrict__ x4,
                                               const v4f* __restrict__ t4,
                                               v4f* __restrict__ o4) {
    int b = blockIdx.y;
    int idx = (blockIdx.x * 256 + threadIdx.x) * 2;  // 0 .. N*C/4-1, step 2
    int c4a = idx & 127;
    size_t off = (size_t)b * (Nn * (Cc / 4)) + idx;
    v4f xv0 = __builtin_nontemporal_load(&x4[off]);
    v4f xv1 = __builtin_nontemporal_load(&x4[off + 1]);
    v4f tv0 = t4[b * (Cc / 4) + c4a];
    v4f tv1 = t4[b * (Cc / 4) + c4a + 1];
    v4f o0 = xv0 + tv0;
    v4f o1 = xv1 + tv1;
    __builtin_nontemporal_store(o0, &o4[off]);
    __builtin_nontemporal_store(o1, &o4[off + 1]);
}

extern "C" void kernel_launch(void* const* d_in, const int* in_sizes, int n_in,
                              void* d_out, int out_size, void* d_ws, size_t ws_size,
                              hipStream_t stream) {
    const float* x      = (const float*)d_in[0];
    const float* w_mask = (const float*)d_in[1];
    const float* b_mask = (const float*)d_in[2];
    const float* w1     = (const float*)d_in[3];
    const float* b1     = (const float*)d_in[4];
    const float* gamma  = (const float*)d_in[5];
    const float* beta   = (const float*)d_in[6];
    const float* w2     = (const float*)d_in[7];
    const float* b2     = (const float*)d_in[8];
    float* out = (float*)d_out;

    float* ws   = (float*)d_ws;
    float* pctx = ws;                                   // B*NCH*C = 524288
    float* pms  = pctx + (size_t)Bb * NCH * Cc;         // B*G*NCH*2 = 16384
    float* tvec = pms + (size_t)Bb * Gg * NCH * 2;      // B*C = 8192

    k_pool<<<dim3(NCH, Bb), 256, 0, stream>>>(x, w_mask, b_mask, pctx, pms);
    k_mlp<<<Bb, Cc, 0, stream>>>(pctx, pms, w1, b1, gamma, beta, w2, b2, tvec);
    k_resid<<<dim3((Nn * Cc / 4) / 512, Bb), 256, 0, stream>>>(
        (const v4f*)x, (const v4f*)tvec, (v4f*)out);
}